// Round 1
// baseline (47.771 us; speedup 1.0000x reference)
//
#include <hip/hip_runtime.h>
#include <hip/hip_bf16.h>
#include <stdint.h>

// SVR polynomial-kernel prediction:
//   out[m] = sum_n alpha[n] * (1 + x_p[m].X[n])^4 + b
// m=16384, n=8192, d=64, all fp32 in/out.
// Strategy: convert inputs to bf16 (RNE), compute K-tiles with
// mfma_f32_16x16x32_bf16 (both operands row-major [*,64] = "B^T" layout),
// apply (1+s)^4 * alpha in-register, fold over n, shuffle-reduce cols.

typedef __attribute__((ext_vector_type(8))) short bf16x8;
typedef __attribute__((ext_vector_type(4))) float f32x4;

#define MM 16384
#define NN 8192
#define DD 64
#define NSPLIT 16
#define NC (NN / NSPLIT)   // 512 n per wave
#define MT 4               // 4 m-tiles of 16 rows => 64 rows per wave
#define MROWS 64

__device__ __forceinline__ unsigned short f2bf(float f) {
    uint32_t u = __float_as_uint(f);
    uint32_t r = (u + 0x7FFFu + ((u >> 16) & 1u)) >> 16;  // round-to-nearest-even
    return (unsigned short)r;
}

__global__ void convert_kernel(const float* __restrict__ xp,
                               const float* __restrict__ X,
                               unsigned short* __restrict__ xbf,
                               unsigned short* __restrict__ Xbf) {
    const int xp4 = MM * DD / 4;          // 262144 float4s
    const int tot4 = xp4 + NN * DD / 4;   // 393216
    int stride = gridDim.x * blockDim.x;
    for (int i = blockIdx.x * blockDim.x + threadIdx.x; i < tot4; i += stride) {
        const float4* src;
        unsigned short* dst;
        int off;
        if (i < xp4) { src = (const float4*)xp; dst = xbf; off = i; }
        else         { src = (const float4*)X;  dst = Xbf; off = i - xp4; }
        float4 v = src[off];
        ushort4 o;
        o.x = f2bf(v.x); o.y = f2bf(v.y); o.z = f2bf(v.z); o.w = f2bf(v.w);
        *(ushort4*)(dst + (size_t)off * 4) = o;
    }
}

__global__ __launch_bounds__(256) void svr_main(
        const unsigned short* __restrict__ xbf,
        const unsigned short* __restrict__ Xbf,
        const float* __restrict__ alpha,
        float* __restrict__ partials) {
    const int lane = threadIdx.x & 63;
    const int gw = (blockIdx.x << 2) + (threadIdx.x >> 6);  // global wave id
    const int mgroup = gw >> 4;            // 0..255  (gw / NSPLIT)
    const int nchunk = gw & (NSPLIT - 1);  // 0..15

    const int r = lane & 15;   // A row within tile / B col within tile
    const int g = lane >> 4;   // k-block selector (k = g*8 + j)

    // Load A fragments for 4 m-tiles (held in registers for whole sweep)
    bf16x8 a[MT][2];
#pragma unroll
    for (int mt = 0; mt < MT; ++mt) {
        const unsigned short* p =
            xbf + (size_t)(mgroup * MROWS + mt * 16 + r) * DD + g * 8;
        a[mt][0] = *(const bf16x8*)p;          // k = 0..31 slice
        a[mt][1] = *(const bf16x8*)(p + 32);   // k = 32..63 slice
    }

    f32x4 red[MT];
#pragma unroll
    for (int mt = 0; mt < MT; ++mt) red[mt] = (f32x4){0.f, 0.f, 0.f, 0.f};

    const int nbase = nchunk * NC;
    for (int nt = 0; nt < NC / 16; ++nt) {
        const int n0 = nbase + nt * 16;
        const unsigned short* q = Xbf + (size_t)(n0 + r) * DD + g * 8;
        bf16x8 b0 = *(const bf16x8*)q;
        bf16x8 b1 = *(const bf16x8*)(q + 32);
        float av = alpha[n0 + r];  // alpha for this lane's output column
#pragma unroll
        for (int mt = 0; mt < MT; ++mt) {
            f32x4 acc = (f32x4){0.f, 0.f, 0.f, 0.f};
            acc = __builtin_amdgcn_mfma_f32_16x16x32_bf16(a[mt][0], b0, acc, 0, 0, 0);
            acc = __builtin_amdgcn_mfma_f32_16x16x32_bf16(a[mt][1], b1, acc, 0, 0, 0);
            // epilogue: red += alpha[col] * (1 + s)^4
#pragma unroll
            for (int i = 0; i < 4; ++i) {
                float t = 1.0f + acc[i];
                float t2 = t * t;
                float t4 = t2 * t2;
                red[mt][i] = fmaf(av, t4, red[mt][i]);
            }
        }
    }

    // Reduce across the 16 column-lanes (lane&15); rows live at (g*4+i).
#pragma unroll
    for (int mt = 0; mt < MT; ++mt) {
#pragma unroll
        for (int i = 0; i < 4; ++i) {
            float v = red[mt][i];
            v += __shfl_xor(v, 1);
            v += __shfl_xor(v, 2);
            v += __shfl_xor(v, 4);
            v += __shfl_xor(v, 8);
            red[mt][i] = v;
        }
    }
    if (r == 0) {
#pragma unroll
        for (int mt = 0; mt < MT; ++mt) {
#pragma unroll
            for (int i = 0; i < 4; ++i) {
                int row = mgroup * MROWS + mt * 16 + g * 4 + i;
                partials[(size_t)nchunk * MM + row] = red[mt][i];
            }
        }
    }
}

__global__ void finalize_kernel(const float* __restrict__ partials,
                                const float* __restrict__ bbias,
                                float* __restrict__ out) {
    int m = blockIdx.x * blockDim.x + threadIdx.x;
    if (m < MM) {
        float s = bbias[0];
#pragma unroll
        for (int c = 0; c < NSPLIT; ++c) s += partials[(size_t)c * MM + m];
        out[m] = s;
    }
}

extern "C" void kernel_launch(void* const* d_in, const int* in_sizes, int n_in,
                              void* d_out, int out_size, void* d_ws, size_t ws_size,
                              hipStream_t stream) {
    const float* xp    = (const float*)d_in[0];
    const float* X     = (const float*)d_in[1];
    const float* alpha = (const float*)d_in[2];
    const float* b     = (const float*)d_in[3];
    float* out = (float*)d_out;

    // ws layout: xbf 2MB | Xbf 1MB | partials NSPLIT*MM*4 = 1MB  (total 4MB)
    unsigned short* xbf = (unsigned short*)d_ws;
    unsigned short* Xbf = xbf + (size_t)MM * DD;
    float* partials = (float*)(Xbf + (size_t)NN * DD);

    hipLaunchKernelGGL(convert_kernel, dim3(1024), dim3(256), 0, stream,
                       xp, X, xbf, Xbf);

    const int waves = (MM / MROWS) * NSPLIT;  // 4096 waves
    hipLaunchKernelGGL(svr_main, dim3(waves / 4), dim3(256), 0, stream,
                       xbf, Xbf, alpha, partials);

    hipLaunchKernelGGL(finalize_kernel, dim3(MM / 256), dim3(256), 0, stream,
                       partials, b, out);
}